// Round 10
// baseline (172.397 us; speedup 1.0000x reference)
//
#include <hip/hip_runtime.h>
#include <hip/hip_fp16.h>
#include <stdint.h>

// LightGCNConv: out[row] += x[col] * edge_weight[e]
// x:[N,64] f32, edge_index:[2,E] int32, edge_weight:[E] f32, out:[N,64] f32.
//
// Pipeline (v10 — col-phased gather for L2 window locality):
//  1) prep: chunk-sort 4096 edges into <=32 superbuckets (4096 rows).
//     Runs ~164 entries -> full-line 8B stores. (v9: prep left top-5.)
//  2) bin2: superbucket chunk -> 64 fine buckets (64 rows), coalesced.
//  3) bucket_acc: v9 measured FETCH 145MB = L2 capacity misses on the
//     12.8MB xb table (4MB L2/XCD -> 31% hit; 205MB * 0.69 = 142MB,
//     matches). v10 splits the gather into 2 col-phases (6.4MB window,
//     ~62% hit): per-(row,phase) CSR sub-lists (24 slots each) built at
//     CSR time; PHASE-MAJOR accumulation (phase outer, 16 rows inner,
//     acc[16] in registers, fully unrolled) so all resident blocks walk
//     the same col window together.

typedef unsigned long long ull;
typedef int   v4i __attribute__((ext_vector_type(4)));
typedef float v4f __attribute__((ext_vector_type(4)));
typedef unsigned char  uchar;

#define RB      64       // rows per fine bucket
#define CAP     1280     // entries per fine-bucket segment; mean 1024 (+8s)
#define CHUNK   4096     // edges per sort block (512 thr x 8)
#define EPT     8        // entries per thread
#define SLOTS   48       // padded-CSR slots per row
#define HSLOT   24       // slots per (row,phase); Poisson(8), P(>24)~1e-6
#define BPAD    16       // counter stride in ints (64B lines)
#define OVF_CAP 65536
#define NSBP    32       // max superbuckets (N <= 131072)
#define SBROWS  4096     // rows per superbucket

__device__ __forceinline__ unsigned short f2bf(float f) {
    union { float f; unsigned int u; } c;
    c.f = f;
    unsigned int lsb = (c.u >> 16) & 1u;
    c.u += 0x7fffu + lsb;
    return (unsigned short)(c.u >> 16);
}
__device__ __forceinline__ float bf2f(unsigned short u) {
    union { unsigned int u; float f; } c;
    c.u = ((unsigned int)u) << 16;
    return c.f;
}
__device__ __forceinline__ float unpack_w(unsigned v) {
    return __half2float(__ushort_as_half((unsigned short)((v & 0x7fffu) << 1)));
}

// ---------- pass 1: chunk -> superbucket sort | x->bf16 convert ----------
// entry fmt seg1: [hw:16 @48][row:17 @24][col:17 @0]
__global__ __launch_bounds__(512) void prep(
    const int* __restrict__ ei, const float* __restrict__ ew,
    int* __restrict__ bcnt1, ull* __restrict__ seg1, int cap1,
    int* __restrict__ ovf_cnt, int3* __restrict__ ovf, int E, int nbin,
    const float* __restrict__ x, unsigned short* __restrict__ xb, int n4)
{
    __shared__ int hist[NSBP];
    __shared__ int lstart[NSBP];
    __shared__ int gbase[NSBP];
    __shared__ ull sorted[CHUNK];     // 32 KB
    int t = threadIdx.x;

    if ((int)blockIdx.x >= nbin) {
        // ---- convert part: 4096 v4f per block ----
        int i0 = ((int)blockIdx.x - nbin) * 4096 + t;
#pragma unroll
        for (int k = 0; k < 8; ++k) {
            int i = i0 + k * 512;
            if (i < n4) {
                v4f v = ((const v4f*)x)[i];
                ushort4 o;
                o.x = f2bf(v.x); o.y = f2bf(v.y);
                o.z = f2bf(v.z); o.w = f2bf(v.w);
                ((ushort4*)xb)[i] = o;
            }
        }
        return;
    }

    if (t < NSBP) hist[t] = 0;
    __syncthreads();

    int e0   = blockIdx.x * CHUNK;
    int nval = E - e0; if (nval > CHUNK) nval = CHUNK;
    bool al4 = ((E & 3) == 0);

    int   rk[EPT];
    uchar sb[EPT];
    ull   cw[EPT];
    bool  vd[EPT];
#pragma unroll
    for (int j = 0; j < EPT / 4; ++j) {
        int eb = e0 + (j * 512 + t) * 4;
        v4i r4, c4; v4f w4;
        if (al4 && eb + 3 < E) {
            r4 = *(const v4i*)(ei + eb);
            c4 = *(const v4i*)(ei + E + eb);
            w4 = *(const v4f*)(ew + eb);
        } else {
#pragma unroll
            for (int u = 0; u < 4; ++u) {
                int e = eb + u;
                r4[u] = e < E ? ei[e] : 0;
                c4[u] = e < E ? ei[E + e] : 0;
                w4[u] = e < E ? ew[e] : 0.f;
            }
        }
#pragma unroll
        for (int u = 0; u < 4; ++u) {
            int idx = j * 4 + u;
            int e = eb + u;
            vd[idx] = e < E;
            int b = r4[u] >> 12;
            rk[idx] = vd[idx] ? atomicAdd(&hist[b], 1) : 0;   // LDS native
            sb[idx] = (uchar)b;
            unsigned hw = __half_as_ushort(__float2half(w4[u]));
            cw[idx] = ((ull)hw << 48) | ((ull)(unsigned)r4[u] << 24) |
                      (ull)(unsigned)c4[u];
        }
    }
    __syncthreads();

    // reservations + exclusive scan, single wave (t<32)
    if (t < 32) {
        int h = hist[t];
        gbase[t] = h ? atomicAdd(&bcnt1[t * BPAD], h) : 0;
        int s = h;
#pragma unroll
        for (int off = 1; off < 32; off <<= 1) {
            int o = __shfl_up(s, off);
            if (t >= off) s += o;
        }
        lstart[t] = s - h;
    }
    __syncthreads();

    // place sorted in LDS
#pragma unroll
    for (int j = 0; j < EPT; ++j) {
        if (!vd[j]) continue;
        sorted[lstart[sb[j]] + rk[j]] = cw[j];
    }
    __syncthreads();

    // sweep store: runs ~CHUNK/NSB = 164 entries -> full-line stores
    for (int i = t; i < nval; i += 512) {
        ull e = sorted[i];
        int b = (int)((e >> 24) & 0x1FFFF) >> 12;
        int loc = gbase[b] + (i - lstart[b]);
        if (loc < cap1) {
            seg1[(size_t)b * cap1 + loc] = e;
        } else {
            int o = atomicAdd(ovf_cnt, 1);
            if (o < OVF_CAP)
                ovf[o] = make_int3((int)((e >> 24) & 0x1FFFF),
                                   (int)(e & 0x1FFFF),
                                   __float_as_int(__half2float(
                                       __ushort_as_half((unsigned short)(e >> 48)))));
        }
    }
}

// ---------- pass 2: superbucket chunk -> fine-bucket sort ----------
// seg2 entry fmt: [hw:16 @32][rl:6 @17][col:17 @0]
__global__ __launch_bounds__(512) void bin2(
    const ull* __restrict__ seg1, int cap1, const int* __restrict__ bcnt1,
    int* __restrict__ bcnt, ull* __restrict__ seg2,
    int* __restrict__ ovf_cnt, int3* __restrict__ ovf, int chpersb)
{
    __shared__ int hist[64];
    __shared__ int lstart[64];
    __shared__ int gbase[64];
    __shared__ ull sorted[CHUNK];     // 32 KB
    int t  = threadIdx.x;
    int sb = blockIdx.x / chpersb;
    int ch = blockIdx.x % chpersb;

    int cnt1 = bcnt1[sb * BPAD];
    if (cnt1 > cap1) cnt1 = cap1;
    int s0 = ch * CHUNK;
    int nval = cnt1 - s0;
    if (nval <= 0) return;
    if (nval > CHUNK) nval = CHUNK;

    if (t < 64) hist[t] = 0;
    __syncthreads();

    const ull* base = seg1 + (size_t)sb * cap1 + s0;

    int   rk[EPT];
    uchar fb[EPT];
    ull   cw[EPT];
    bool  vd[EPT];
#pragma unroll
    for (int j = 0; j < EPT; ++j) {
        int i = t + j * 512;                 // coalesced 8B reads
        vd[j] = i < nval;
        ull e = vd[j] ? base[i] : 0;
        int row = (int)((e >> 24) & 0x1FFFF);
        int f = (row >> 6) & 63;
        rk[j] = vd[j] ? atomicAdd(&hist[f], 1) : 0;   // LDS native
        fb[j] = (uchar)f;
        cw[j] = e;
    }
    __syncthreads();

    // reservations + exclusive scan, single wave (t<64)
    if (t < 64) {
        int h = hist[t];
        int fbg = sb * 64 + t;
        gbase[t] = h ? atomicAdd(&bcnt[fbg * BPAD], h) : 0;
        int s = h;
#pragma unroll
        for (int off = 1; off < 64; off <<= 1) {
            int o = __shfl_up(s, off);
            if (t >= off) s += o;
        }
        lstart[t] = s - h;
    }
    __syncthreads();

#pragma unroll
    for (int j = 0; j < EPT; ++j) {
        if (!vd[j]) continue;
        sorted[lstart[fb[j]] + rk[j]] = cw[j];
    }
    __syncthreads();

    // sweep store: runs ~CHUNK/64 = 64 entries (512B) -> coalesced
    for (int i = t; i < nval; i += 512) {
        ull e = sorted[i];
        int row = (int)((e >> 24) & 0x1FFFF);
        int f = (row >> 6) & 63;
        int loc = gbase[f] + (i - lstart[f]);
        int fbg = sb * 64 + f;
        if (loc < CAP) {
            ull hw = (e >> 48) & 0xFFFF;
            seg2[(size_t)fbg * CAP + loc] =
                (hw << 32) | ((ull)(unsigned)(row & 63) << 17) |
                (e & 0x1FFFF);
        } else {
            int o = atomicAdd(ovf_cnt, 1);
            if (o < OVF_CAP)
                ovf[o] = make_int3(row, (int)(e & 0x1FFFF),
                                   __float_as_int(__half2float(
                                       __ushort_as_half((unsigned short)(e >> 48)))));
        }
    }
}

// ---------- phase 3: seg2 -> phase-split LDS CSR -> register acc -> out --
// 256 thr (4 waves), ~12.8 KB LDS, 8 blocks/CU cap, grid ~1563.
template <bool BF>
__global__ __launch_bounds__(256, 8) void bucket_acc(
    const void* __restrict__ xv, const ull* __restrict__ seg2,
    const int* __restrict__ bcnt, float* __restrict__ out,
    int* __restrict__ ovf_cnt, int3* __restrict__ ovf, int N)
{
    __shared__ int      cur2[RB * 2];       // per-(row,phase) cursors
    __shared__ unsigned tile[RB * SLOTS];   // 12 KB; row-major, phase-split
    int t = threadIdx.x;
    int g = blockIdx.x;
    if (t < RB * 2) cur2[t] = 0;
    __syncthreads();

    int nhalf = N >> 1;
    int c = bcnt[g * BPAD];
    if (c > CAP) c = CAP;
    const ull* b8 = seg2 + (size_t)g * CAP;

    // build phase-split LDS CSR
    for (int i = t; i < c; i += 256) {
        ull e = b8[i];
        int rl = (int)((e >> 17) & 63);
        unsigned p4 = ((unsigned)(e & 0x1FFFF) << 15) |
                      ((unsigned)(e >> 33) & 0x7FFF);
        int col = (int)(e & 0x1FFFF);
        int ph  = col >= nhalf ? 1 : 0;
        int pos = atomicAdd(&cur2[rl * 2 + ph], 1);   // native LDS int atomic
        if (pos < HSLOT) {
            tile[rl * SLOTS + ph * HSLOT + pos] = p4;
        } else {
            int o = atomicAdd(ovf_cnt, 1);
            if (o < OVF_CAP)
                ovf[o] = make_int3(g * RB + rl, col,
                                   __float_as_int(unpack_w(p4)));
        }
    }
    __syncthreads();

    // phase-major register accumulation: phase outer, 16 rows inner,
    // acc[16] fully unrolled (static indices -> registers).
    int wid  = t >> 6;
    int lane = t & 63;
    const unsigned short* xh = (const unsigned short*)xv;
    const float*          xf = (const float*)xv;

    float acc[16];
#pragma unroll
    for (int k = 0; k < 16; ++k) acc[k] = 0.0f;

#pragma unroll
    for (int ph = 0; ph < 2; ++ph) {
#pragma unroll
        for (int k = 0; k < 16; ++k) {
            int r   = wid * 16 + k;
            int row = g * RB + r;
            if (row >= N) continue;
            int cc = cur2[r * 2 + ph];
            if (cc > HSLOT) cc = HSLOT;
            const unsigned* tb = &tile[r * SLOTS + ph * HSLOT];

            int p = 0;
            for (; p + 8 <= cc; p += 8) {
                unsigned a[8]; float xr[8];
#pragma unroll
                for (int i = 0; i < 8; ++i) a[i] = tb[p + i];  // broadcast
#pragma unroll
                for (int i = 0; i < 8; ++i) {
                    size_t off = (((size_t)(a[i] >> 15)) << 6) + lane;
                    xr[i] = BF ? bf2f(xh[off]) : xf[off];
                }
#pragma unroll
                for (int i = 0; i < 8; ++i)
                    acc[k] = fmaf(xr[i], unpack_w(a[i]), acc[k]);
            }
            if (p < cc) {   // masked 8-group tail (cc >= 1 here)
                unsigned a[8]; float xr[8], w[8];
#pragma unroll
                for (int i = 0; i < 8; ++i) {
                    int q = p + i;
                    bool valid = q < cc;
                    if (!valid) q = cc - 1;
                    a[i] = tb[q];
                    w[i] = valid ? unpack_w(a[i]) : 0.0f;
                }
#pragma unroll
                for (int i = 0; i < 8; ++i) {
                    size_t off = (((size_t)(a[i] >> 15)) << 6) + lane;
                    xr[i] = BF ? bf2f(xh[off]) : xf[off];
                }
#pragma unroll
                for (int i = 0; i < 8; ++i)
                    acc[k] = fmaf(xr[i], w[i], acc[k]);
            }
        }
    }

#pragma unroll
    for (int k = 0; k < 16; ++k) {
        int row = g * RB + wid * 16 + k;
        if (row < N)
            __builtin_nontemporal_store(acc[k],
                out + (((size_t)row) << 6) + lane);
    }
}

// ---------- overflow fixup (normally 0 edges) ----------
template <bool BF>
__global__ __launch_bounds__(256) void ovf_apply(
    const void* __restrict__ xv, const int* __restrict__ ovf_cnt,
    const int3* __restrict__ ovf, float* __restrict__ out)
{
    int n = *ovf_cnt;
    if (n > OVF_CAP) n = OVF_CAP;
    int wid  = (blockIdx.x * 256 + threadIdx.x) >> 6;
    int lane = threadIdx.x & 63;
    int nw   = gridDim.x * 4;
    for (int o = wid; o < n; o += nw) {
        int3 tt = ovf[o];
        float w = __int_as_float(tt.z);
        size_t off = (((size_t)tt.y) << 6) + lane;
        float x = BF ? bf2f(((const unsigned short*)xv)[off])
                     : ((const float*)xv)[off];
        atomicAdd(&out[(((size_t)tt.x) << 6) + lane], x * w);
    }
}

// ---------- fallback: direct atomic scatter ----------
__global__ __launch_bounds__(256) void scatter_edges(
    const float* __restrict__ x, const int* __restrict__ ei,
    const float* __restrict__ ew, float* __restrict__ out, int E)
{
    long long idx = (long long)blockIdx.x * 256 + threadIdx.x;
    int e = (int)(idx >> 4);
    if (e >= E) return;
    int j = (int)(idx & 15);
    int row = ei[e];
    int col = ei[E + e];
    float w = ew[e];
    v4f v = *(const v4f*)(x + (((size_t)col) << 6) + (j << 2));
    float* op = out + (((size_t)row) << 6) + (j << 2);
    atomicAdd(op + 0, v.x * w);
    atomicAdd(op + 1, v.y * w);
    atomicAdd(op + 2, v.z * w);
    atomicAdd(op + 3, v.w * w);
}

extern "C" void kernel_launch(void* const* d_in, const int* in_sizes, int n_in,
                              void* d_out, int out_size, void* d_ws, size_t ws_size,
                              hipStream_t stream) {
    const float* x  = (const float*)d_in[0];
    const int*   ei = (const int*)d_in[1];
    const float* ew = (const float*)d_in[2];
    float*       out = (float*)d_out;

    int E = in_sizes[2];
    int N = out_size / 64;
    int NB  = (N + RB - 1) / RB;
    int NSB = (N + SBROWS - 1) / SBROWS;

    long long mean1 = (long long)E * SBROWS / (N > 0 ? N : 1);
    int cap1 = (int)(mean1 + mean1 / 20 + CHUNK);
    cap1 = (cap1 + 1023) & ~1023;
    int chpersb = (cap1 + CHUNK - 1) / CHUNK;

    // ws (ints): bcnt1[32*BPAD] | bcnt[NB*BPAD] | ovf_cnt | pad |
    //            ovf[3*OVF] | xb[N*32] | seg1[NSB*cap1*2] | seg2[NB*CAP*2]
    size_t bcnt_base = (size_t)NSBP * BPAD;
    size_t ovfc_base = bcnt_base + (size_t)NB * BPAD;
    size_t ovf_base  = (ovfc_base + 1 + 3) & ~(size_t)3;
    size_t xb_base   = (ovf_base + 3 * (size_t)OVF_CAP + 3) & ~(size_t)3;
    size_t seg1_base = (xb_base + (size_t)N * 32 + 1) & ~(size_t)1;
    size_t seg2_base = seg1_base + (size_t)NSB * cap1 * 2;
    size_t need      = (seg2_base + (size_t)NB * CAP * 2) * 4;

    int nbin  = (E + CHUNK - 1) / CHUNK;
    int n4    = (N * 64) / 4;
    int nconv = (n4 + CHUNK - 1) / CHUNK;

    if (ws_size >= need && N <= (1 << 17)) {
        int* w32 = (int*)d_ws;
        int* bcnt1   = w32;
        int* bcnt    = w32 + bcnt_base;
        int* ovf_cnt = w32 + ovfc_base;
        int3* ovf    = (int3*)(w32 + ovf_base);
        unsigned short* xb = (unsigned short*)(w32 + xb_base);
        ull* seg1 = (ull*)(w32 + seg1_base);
        ull* seg2 = (ull*)(w32 + seg2_base);

        (void)hipMemsetAsync(w32, 0,
            (bcnt_base + (size_t)NB * BPAD + 2) * sizeof(int), stream);

        prep<<<nbin + nconv, 512, 0, stream>>>(
            ei, ew, bcnt1, seg1, cap1, ovf_cnt, ovf, E, nbin, x, xb, n4);
        bin2<<<NSB * chpersb, 512, 0, stream>>>(
            seg1, cap1, bcnt1, bcnt, seg2, ovf_cnt, ovf, chpersb);
        bucket_acc<true><<<NB, 256, 0, stream>>>(
            xb, seg2, bcnt, out, ovf_cnt, ovf, N);
        ovf_apply<true><<<64, 256, 0, stream>>>(xb, ovf_cnt, ovf, out);
    } else {
        (void)hipMemsetAsync(out, 0, (size_t)out_size * sizeof(float), stream);
        long long threads = (long long)E * 16;
        scatter_edges<<<(int)((threads + 255) / 256), 256, 0, stream>>>(
            x, ei, ew, out, E);
    }
}

// Round 12
// 163.265 us; speedup vs baseline: 1.0559x; 1.0559x over previous
//
#include <hip/hip_runtime.h>
#include <hip/hip_fp16.h>
#include <stdint.h>

// LightGCNConv: out[row] += x[col] * edge_weight[e]
// x:[N,64] f32, edge_index:[2,E] int32, edge_weight:[E] f32, out:[N,64] f32.
//
// Pipeline (v11b — dual-edge gathers; fixed nontemporal ext-vector store):
//  v10 post-mortem: phase-split cut FETCH 145->92MB but dur ROSE 51.5->64us
//  -> bucket_acc is ISSUE-bound (1.6M gather instrs + ~10 VALU each;
//  VALUBusy 56% = 29us of issue), not fetch-bound. v11 reverts phases and
//  halves the instruction stream instead: one gather instruction fetches
//  TWO edges' rows (lanes 0-31 = edge A, lanes 32-63 = edge B, ushort2 =
//  2 dims/lane), final __shfl_xor(32) fold + float2 half-wave store.
//  1) prep: chunk-sort 4096 edges into <=32 superbuckets (full-line 8B
//     stores; v9-proven). 2) bin2: superbucket -> 64-row fine buckets.
//  3) bucket_acc: seg2 -> LDS padded-CSR -> dual-edge register acc.

typedef unsigned long long ull;
typedef int   v4i __attribute__((ext_vector_type(4)));
typedef float v4f __attribute__((ext_vector_type(4)));
typedef float v2f __attribute__((ext_vector_type(2)));   // nontemporal-safe
typedef unsigned char  uchar;

#define RB      64       // rows per fine bucket
#define CAP     1280     // entries per fine-bucket segment; mean 1024 (+8s)
#define CHUNK   4096     // edges per sort block (512 thr x 8)
#define EPT     8        // entries per thread
#define SLOTS   48       // padded-CSR slots per row (deg ~Poisson(16))
#define BPAD    16       // counter stride in ints (64B lines)
#define OVF_CAP 65536
#define NSBP    32       // max superbuckets (N <= 131072)
#define SBROWS  4096     // rows per superbucket

__device__ __forceinline__ unsigned short f2bf(float f) {
    union { float f; unsigned int u; } c;
    c.f = f;
    unsigned int lsb = (c.u >> 16) & 1u;
    c.u += 0x7fffu + lsb;
    return (unsigned short)(c.u >> 16);
}
__device__ __forceinline__ float bf2f(unsigned short u) {
    union { unsigned int u; float f; } c;
    c.u = ((unsigned int)u) << 16;
    return c.f;
}
__device__ __forceinline__ float unpack_w(unsigned v) {
    return __half2float(__ushort_as_half((unsigned short)((v & 0x7fffu) << 1)));
}

// ---------- pass 1: chunk -> superbucket sort | x->bf16 convert ----------
// entry fmt seg1: [hw:16 @48][row:17 @24][col:17 @0]
__global__ __launch_bounds__(512) void prep(
    const int* __restrict__ ei, const float* __restrict__ ew,
    int* __restrict__ bcnt1, ull* __restrict__ seg1, int cap1,
    int* __restrict__ ovf_cnt, int3* __restrict__ ovf, int E, int nbin,
    const float* __restrict__ x, unsigned short* __restrict__ xb, int n4)
{
    __shared__ int hist[NSBP];
    __shared__ int lstart[NSBP];
    __shared__ int gbase[NSBP];
    __shared__ ull sorted[CHUNK];     // 32 KB
    int t = threadIdx.x;

    if ((int)blockIdx.x >= nbin) {
        // ---- convert part: 4096 v4f per block ----
        int i0 = ((int)blockIdx.x - nbin) * 4096 + t;
#pragma unroll
        for (int k = 0; k < 8; ++k) {
            int i = i0 + k * 512;
            if (i < n4) {
                v4f v = ((const v4f*)x)[i];
                ushort4 o;
                o.x = f2bf(v.x); o.y = f2bf(v.y);
                o.z = f2bf(v.z); o.w = f2bf(v.w);
                ((ushort4*)xb)[i] = o;
            }
        }
        return;
    }

    if (t < NSBP) hist[t] = 0;
    __syncthreads();

    int e0   = blockIdx.x * CHUNK;
    int nval = E - e0; if (nval > CHUNK) nval = CHUNK;
    bool al4 = ((E & 3) == 0);

    int   rk[EPT];
    uchar sb[EPT];
    ull   cw[EPT];
    bool  vd[EPT];
#pragma unroll
    for (int j = 0; j < EPT / 4; ++j) {
        int eb = e0 + (j * 512 + t) * 4;
        v4i r4, c4; v4f w4;
        if (al4 && eb + 3 < E) {
            r4 = *(const v4i*)(ei + eb);
            c4 = *(const v4i*)(ei + E + eb);
            w4 = *(const v4f*)(ew + eb);
        } else {
#pragma unroll
            for (int u = 0; u < 4; ++u) {
                int e = eb + u;
                r4[u] = e < E ? ei[e] : 0;
                c4[u] = e < E ? ei[E + e] : 0;
                w4[u] = e < E ? ew[e] : 0.f;
            }
        }
#pragma unroll
        for (int u = 0; u < 4; ++u) {
            int idx = j * 4 + u;
            int e = eb + u;
            vd[idx] = e < E;
            int b = r4[u] >> 12;
            rk[idx] = vd[idx] ? atomicAdd(&hist[b], 1) : 0;   // LDS native
            sb[idx] = (uchar)b;
            unsigned hw = __half_as_ushort(__float2half(w4[u]));
            cw[idx] = ((ull)hw << 48) | ((ull)(unsigned)r4[u] << 24) |
                      (ull)(unsigned)c4[u];
        }
    }
    __syncthreads();

    // reservations + exclusive scan, single wave (t<32)
    if (t < 32) {
        int h = hist[t];
        gbase[t] = h ? atomicAdd(&bcnt1[t * BPAD], h) : 0;
        int s = h;
#pragma unroll
        for (int off = 1; off < 32; off <<= 1) {
            int o = __shfl_up(s, off);
            if (t >= off) s += o;
        }
        lstart[t] = s - h;
    }
    __syncthreads();

    // place sorted in LDS
#pragma unroll
    for (int j = 0; j < EPT; ++j) {
        if (!vd[j]) continue;
        sorted[lstart[sb[j]] + rk[j]] = cw[j];
    }
    __syncthreads();

    // sweep store: runs ~CHUNK/NSB = 164 entries -> full-line stores
    for (int i = t; i < nval; i += 512) {
        ull e = sorted[i];
        int b = (int)((e >> 24) & 0x1FFFF) >> 12;
        int loc = gbase[b] + (i - lstart[b]);
        if (loc < cap1) {
            seg1[(size_t)b * cap1 + loc] = e;
        } else {
            int o = atomicAdd(ovf_cnt, 1);
            if (o < OVF_CAP)
                ovf[o] = make_int3((int)((e >> 24) & 0x1FFFF),
                                   (int)(e & 0x1FFFF),
                                   __float_as_int(__half2float(
                                       __ushort_as_half((unsigned short)(e >> 48)))));
        }
    }
}

// ---------- pass 2: superbucket chunk -> fine-bucket sort ----------
// seg2 entry fmt: [hw:16 @32][rl:6 @17][col:17 @0]
__global__ __launch_bounds__(512) void bin2(
    const ull* __restrict__ seg1, int cap1, const int* __restrict__ bcnt1,
    int* __restrict__ bcnt, ull* __restrict__ seg2,
    int* __restrict__ ovf_cnt, int3* __restrict__ ovf, int chpersb)
{
    __shared__ int hist[64];
    __shared__ int lstart[64];
    __shared__ int gbase[64];
    __shared__ ull sorted[CHUNK];     // 32 KB
    int t  = threadIdx.x;
    int sb = blockIdx.x / chpersb;
    int ch = blockIdx.x % chpersb;

    int cnt1 = bcnt1[sb * BPAD];
    if (cnt1 > cap1) cnt1 = cap1;
    int s0 = ch * CHUNK;
    int nval = cnt1 - s0;
    if (nval <= 0) return;
    if (nval > CHUNK) nval = CHUNK;

    if (t < 64) hist[t] = 0;
    __syncthreads();

    const ull* base = seg1 + (size_t)sb * cap1 + s0;

    int   rk[EPT];
    uchar fb[EPT];
    ull   cw[EPT];
    bool  vd[EPT];
#pragma unroll
    for (int j = 0; j < EPT; ++j) {
        int i = t + j * 512;                 // coalesced 8B reads
        vd[j] = i < nval;
        ull e = vd[j] ? base[i] : 0;
        int row = (int)((e >> 24) & 0x1FFFF);
        int f = (row >> 6) & 63;
        rk[j] = vd[j] ? atomicAdd(&hist[f], 1) : 0;   // LDS native
        fb[j] = (uchar)f;
        cw[j] = e;
    }
    __syncthreads();

    // reservations + exclusive scan, single wave (t<64)
    if (t < 64) {
        int h = hist[t];
        int fbg = sb * 64 + t;
        gbase[t] = h ? atomicAdd(&bcnt[fbg * BPAD], h) : 0;
        int s = h;
#pragma unroll
        for (int off = 1; off < 64; off <<= 1) {
            int o = __shfl_up(s, off);
            if (t >= off) s += o;
        }
        lstart[t] = s - h;
    }
    __syncthreads();

#pragma unroll
    for (int j = 0; j < EPT; ++j) {
        if (!vd[j]) continue;
        sorted[lstart[fb[j]] + rk[j]] = cw[j];
    }
    __syncthreads();

    // sweep store: runs ~CHUNK/64 = 64 entries (512B) -> coalesced
    for (int i = t; i < nval; i += 512) {
        ull e = sorted[i];
        int row = (int)((e >> 24) & 0x1FFFF);
        int f = (row >> 6) & 63;
        int loc = gbase[f] + (i - lstart[f]);
        int fbg = sb * 64 + f;
        if (loc < CAP) {
            ull hw = (e >> 48) & 0xFFFF;
            seg2[(size_t)fbg * CAP + loc] =
                (hw << 32) | ((ull)(unsigned)(row & 63) << 17) |
                (e & 0x1FFFF);
        } else {
            int o = atomicAdd(ovf_cnt, 1);
            if (o < OVF_CAP)
                ovf[o] = make_int3(row, (int)(e & 0x1FFFF),
                                   __float_as_int(__half2float(
                                       __ushort_as_half((unsigned short)(e >> 48)))));
        }
    }
}

// ---------- phase 3: seg2 -> LDS CSR -> DUAL-EDGE register acc -> out ----
// 256 thr (4 waves), ~12.5 KB LDS, 8 blocks/CU cap, grid ~1563.
// One gather instruction fetches TWO edges' rows: lanes 0-31 edge A,
// lanes 32-63 edge B; each lane holds a dim-pair (ushort2 / float2).
template <bool BF>
__global__ __launch_bounds__(256, 8) void bucket_acc(
    const void* __restrict__ xv, const ull* __restrict__ seg2,
    const int* __restrict__ bcnt, float* __restrict__ out,
    int* __restrict__ ovf_cnt, int3* __restrict__ ovf, int N)
{
    __shared__ int      cur[RB];
    __shared__ unsigned tile[RB * SLOTS];   // 12 KB packed col<<15|hw>>1
    int t = threadIdx.x;
    int g = blockIdx.x;
    if (t < RB) cur[t] = 0;
    __syncthreads();

    int c = bcnt[g * BPAD];
    if (c > CAP) c = CAP;
    const ull* b8 = seg2 + (size_t)g * CAP;

    // build LDS CSR: coalesced 8B reads, LDS cursor atomic, LDS write
    for (int i = t; i < c; i += 256) {
        ull e = b8[i];
        int rl = (int)((e >> 17) & 63);
        unsigned p4 = ((unsigned)(e & 0x1FFFF) << 15) |
                      ((unsigned)(e >> 33) & 0x7FFF);
        int pos = atomicAdd(&cur[rl], 1);          // native LDS int atomic
        if (pos < SLOTS) {
            tile[rl * SLOTS + pos] = p4;
        } else {
            int o = atomicAdd(ovf_cnt, 1);
            if (o < OVF_CAP)
                ovf[o] = make_int3(g * RB + rl, (int)(p4 >> 15),
                                   __float_as_int(unpack_w(p4)));
        }
    }
    __syncthreads();

    int wid  = t >> 6;
    int lane = t & 63;
    int half = lane >> 5;    // which edge of the pair this lane serves
    int dp   = lane & 31;    // dim-pair index (dims 2dp, 2dp+1)
    const ushort2* x2h = (const ushort2*)xv;
    const float2*  x2f = (const float2*)xv;

    for (int k = 0; k < 16; ++k) {
        int r   = wid * 16 + k;
        int row = g * RB + r;
        int cc = cur[r];
        if (cc > SLOTS) cc = SLOTS;

        float ax = 0.0f, ay = 0.0f;
        if (cc > 0) {
            const unsigned* tb = &tile[r * SLOTS];
            int p = 0;
            // full groups: 8 pairs = 16 edges, all valid
            for (; p + 16 <= cc; p += 16) {
                unsigned a[8]; float xx[8], xy[8];
#pragma unroll
                for (int i = 0; i < 8; ++i)
                    a[i] = tb[p + 2 * i + half];   // 2-way LDS broadcast
#pragma unroll
                for (int i = 0; i < 8; ++i) {
                    unsigned off = ((a[i] >> 15) << 5) + dp;
                    if (BF) { ushort2 v = x2h[off]; xx[i] = bf2f(v.x); xy[i] = bf2f(v.y); }
                    else    { float2  v = x2f[off]; xx[i] = v.x;       xy[i] = v.y; }
                }
#pragma unroll
                for (int i = 0; i < 8; ++i) {
                    float w = unpack_w(a[i]);
                    ax = fmaf(xx[i], w, ax);
                    ay = fmaf(xy[i], w, ay);
                }
            }
            if (p < cc) {   // masked group (cc >= 1)
                unsigned a[8]; float xx[8], xy[8], w[8];
#pragma unroll
                for (int i = 0; i < 8; ++i) {
                    int q = p + 2 * i + half;
                    bool valid = q < cc;
                    if (!valid) q = cc - 1;
                    a[i] = tb[q];
                    w[i] = valid ? unpack_w(a[i]) : 0.0f;
                }
#pragma unroll
                for (int i = 0; i < 8; ++i) {
                    unsigned off = ((a[i] >> 15) << 5) + dp;
                    if (BF) { ushort2 v = x2h[off]; xx[i] = bf2f(v.x); xy[i] = bf2f(v.y); }
                    else    { float2  v = x2f[off]; xx[i] = v.x;       xy[i] = v.y; }
                }
#pragma unroll
                for (int i = 0; i < 8; ++i) {
                    ax = fmaf(xx[i], w[i], ax);
                    ay = fmaf(xy[i], w[i], ay);
                }
            }
            // fold the two edge-halves: lane l += lane l^32
            ax += __shfl_xor(ax, 32);
            ay += __shfl_xor(ay, 32);
        }
        if (lane < 32 && row < N) {
            v2f o2; o2.x = ax; o2.y = ay;
            __builtin_nontemporal_store(o2,
                ((v2f*)(out + (((size_t)row) << 6))) + dp);
        }
    }
}

// ---------- overflow fixup (normally 0 edges) ----------
template <bool BF>
__global__ __launch_bounds__(256) void ovf_apply(
    const void* __restrict__ xv, const int* __restrict__ ovf_cnt,
    const int3* __restrict__ ovf, float* __restrict__ out)
{
    int n = *ovf_cnt;
    if (n > OVF_CAP) n = OVF_CAP;
    int wid  = (blockIdx.x * 256 + threadIdx.x) >> 6;
    int lane = threadIdx.x & 63;
    int nw   = gridDim.x * 4;
    for (int o = wid; o < n; o += nw) {
        int3 tt = ovf[o];
        float w = __int_as_float(tt.z);
        size_t off = (((size_t)tt.y) << 6) + lane;
        float x = BF ? bf2f(((const unsigned short*)xv)[off])
                     : ((const float*)xv)[off];
        atomicAdd(&out[(((size_t)tt.x) << 6) + lane], x * w);
    }
}

// ---------- fallback: direct atomic scatter ----------
__global__ __launch_bounds__(256) void scatter_edges(
    const float* __restrict__ x, const int* __restrict__ ei,
    const float* __restrict__ ew, float* __restrict__ out, int E)
{
    long long idx = (long long)blockIdx.x * 256 + threadIdx.x;
    int e = (int)(idx >> 4);
    if (e >= E) return;
    int j = (int)(idx & 15);
    int row = ei[e];
    int col = ei[E + e];
    float w = ew[e];
    v4f v = *(const v4f*)(x + (((size_t)col) << 6) + (j << 2));
    float* op = out + (((size_t)row) << 6) + (j << 2);
    atomicAdd(op + 0, v.x * w);
    atomicAdd(op + 1, v.y * w);
    atomicAdd(op + 2, v.z * w);
    atomicAdd(op + 3, v.w * w);
}

extern "C" void kernel_launch(void* const* d_in, const int* in_sizes, int n_in,
                              void* d_out, int out_size, void* d_ws, size_t ws_size,
                              hipStream_t stream) {
    const float* x  = (const float*)d_in[0];
    const int*   ei = (const int*)d_in[1];
    const float* ew = (const float*)d_in[2];
    float*       out = (float*)d_out;

    int E = in_sizes[2];
    int N = out_size / 64;
    int NB  = (N + RB - 1) / RB;
    int NSB = (N + SBROWS - 1) / SBROWS;

    long long mean1 = (long long)E * SBROWS / (N > 0 ? N : 1);
    int cap1 = (int)(mean1 + mean1 / 20 + CHUNK);
    cap1 = (cap1 + 1023) & ~1023;
    int chpersb = (cap1 + CHUNK - 1) / CHUNK;

    // ws (ints): bcnt1[32*BPAD] | bcnt[NB*BPAD] | ovf_cnt | pad |
    //            ovf[3*OVF] | xb[N*32] | seg1[NSB*cap1*2] | seg2[NB*CAP*2]
    size_t bcnt_base = (size_t)NSBP * BPAD;
    size_t ovfc_base = bcnt_base + (size_t)NB * BPAD;
    size_t ovf_base  = (ovfc_base + 1 + 3) & ~(size_t)3;
    size_t xb_base   = (ovf_base + 3 * (size_t)OVF_CAP + 3) & ~(size_t)3;
    size_t seg1_base = (xb_base + (size_t)N * 32 + 1) & ~(size_t)1;
    size_t seg2_base = seg1_base + (size_t)NSB * cap1 * 2;
    size_t need      = (seg2_base + (size_t)NB * CAP * 2) * 4;

    int nbin  = (E + CHUNK - 1) / CHUNK;
    int n4    = (N * 64) / 4;
    int nconv = (n4 + CHUNK - 1) / CHUNK;

    if (ws_size >= need && N <= (1 << 17)) {
        int* w32 = (int*)d_ws;
        int* bcnt1   = w32;
        int* bcnt    = w32 + bcnt_base;
        int* ovf_cnt = w32 + ovfc_base;
        int3* ovf    = (int3*)(w32 + ovf_base);
        unsigned short* xb = (unsigned short*)(w32 + xb_base);
        ull* seg1 = (ull*)(w32 + seg1_base);
        ull* seg2 = (ull*)(w32 + seg2_base);

        (void)hipMemsetAsync(w32, 0,
            (bcnt_base + (size_t)NB * BPAD + 2) * sizeof(int), stream);

        prep<<<nbin + nconv, 512, 0, stream>>>(
            ei, ew, bcnt1, seg1, cap1, ovf_cnt, ovf, E, nbin, x, xb, n4);
        bin2<<<NSB * chpersb, 512, 0, stream>>>(
            seg1, cap1, bcnt1, bcnt, seg2, ovf_cnt, ovf, chpersb);
        bucket_acc<true><<<NB, 256, 0, stream>>>(
            xb, seg2, bcnt, out, ovf_cnt, ovf, N);
        ovf_apply<true><<<64, 256, 0, stream>>>(xb, ovf_cnt, ovf, out);
    } else {
        (void)hipMemsetAsync(out, 0, (size_t)out_size * sizeof(float), stream);
        long long threads = (long long)E * 16;
        scatter_edges<<<(int)((threads + 255) / 256), 256, 0, stream>>>(
            x, ei, ew, out, E);
    }
}